// Round 1
// baseline (1400.790 us; speedup 1.0000x reference)
//
#include <hip/hip_runtime.h>
#include <hip/hip_bf16.h>
#include <math.h>

// Problem constants (match reference)
#define BB 8
#define SS 2048
#define DD 1024
#define DS 64
#define MM (BB*SS)   // 16384

// ---------------- helpers ----------------

__device__ __forceinline__ float4 ld4(const float* p) { return *(const float4*)p; }

template<int CTRL>
__device__ __forceinline__ float dppadd(float x) {
  int v = __builtin_amdgcn_update_dpp(0, __float_as_int(x), CTRL, 0xf, 0xf, true);
  return x + __int_as_float(v);
}

// full 64-lane butterfly sum; result valid in all lanes
__device__ __forceinline__ float wsum(float x) {
  x = dppadd<0xB1>(x);   // quad_perm [1,0,3,2]  (xor 1)
  x = dppadd<0x4E>(x);   // quad_perm [2,3,0,1]  (xor 2)
  x = dppadd<0x141>(x);  // row_half_mirror      (xor 7 -> completes 8-group)
  x = dppadd<0x140>(x);  // row_mirror           (xor 15 -> completes 16-group)
  x += __shfl_xor(x, 16, 64);
  x += __shfl_xor(x, 32, 64);
  return x;
}

__device__ __forceinline__ float gelu_exact(float x) {
  return 0.5f * x * (1.f + erff(x * 0.7071067811865476f));
}

// ---------------- k0: pack weights [Wk;Wv;Wq;ir_w1;pw;0-pad] -> Wcat[320][1024]
__global__ __launch_bounds__(256) void pack_w(
    const float* __restrict__ Wk, const float* __restrict__ Wv,
    const float* __restrict__ Wq, const float* __restrict__ ir_w1,
    const float* __restrict__ pw, float* __restrict__ Wcat) {
  int idx = blockIdx.x * 256 + threadIdx.x;   // 320*1024 total
  int r = idx >> 10, c = idx & 1023;
  float val = 0.f;
  if (r < 64)       val = Wk[r*1024 + c];
  else if (r < 128) val = Wv[(r-64)*1024 + c];
  else if (r < 192) val = Wq[(r-128)*1024 + c];
  else if (r < 256) val = ir_w1[(r-192)*1024 + c];
  else if (r < 259) val = pw[(r-256)*1024 + c];
  Wcat[idx] = val;
}

// ---------------- k1: Y[16384][320] = X[16384][1024] @ Wcat[320][1024]^T
// Mtile=128, Ntile=64, BK=32, 256 threads, micro 8x4 per thread.
__global__ __launch_bounds__(256) void gemm1(
    const float* __restrict__ X, const float* __restrict__ Wcat,
    float* __restrict__ Y) {
  __shared__ float As[32*128];   // [k][m]
  __shared__ float Bs[32*64];    // [k][n]
  const int t  = threadIdx.x;
  const int m0 = blockIdx.x * 128;
  const int n0 = blockIdx.y * 64;
  const int mi = t >> 4, ni = t & 15;
  const int rA = t >> 1, hA = t & 1;   // A staging: row, 16-col half
  const int rB = t >> 2, qB = t & 3;   // B staging: row, 8-col quarter
  float acc[8][4];
  #pragma unroll
  for (int i = 0; i < 8; ++i)
    #pragma unroll
    for (int j = 0; j < 4; ++j) acc[i][j] = 0.f;

  for (int k0 = 0; k0 < 1024; k0 += 32) {
    __syncthreads();
    {
      const float* src = X + (size_t)(m0 + rA)*1024 + k0 + hA*16;
      #pragma unroll
      for (int jj = 0; jj < 4; ++jj) {
        float4 xv = ld4(src + jj*4);
        int kk = hA*16 + jj*4;
        As[(kk+0)*128 + rA] = xv.x; As[(kk+1)*128 + rA] = xv.y;
        As[(kk+2)*128 + rA] = xv.z; As[(kk+3)*128 + rA] = xv.w;
      }
      const float* srcB = Wcat + (size_t)(n0 + rB)*1024 + k0 + qB*8;
      #pragma unroll
      for (int jj = 0; jj < 2; ++jj) {
        float4 bv = ld4(srcB + jj*4);
        int kb = qB*8 + jj*4;
        Bs[(kb+0)*64 + rB] = bv.x; Bs[(kb+1)*64 + rB] = bv.y;
        Bs[(kb+2)*64 + rB] = bv.z; Bs[(kb+3)*64 + rB] = bv.w;
      }
    }
    __syncthreads();
    #pragma unroll
    for (int kk = 0; kk < 32; ++kk) {
      float a[8], bv[4];
      float4 a0 = *(const float4*)&As[kk*128 + mi*8];
      float4 a1 = *(const float4*)&As[kk*128 + mi*8 + 4];
      float4 b0 = *(const float4*)&Bs[kk*64 + ni*4];
      a[0]=a0.x; a[1]=a0.y; a[2]=a0.z; a[3]=a0.w;
      a[4]=a1.x; a[5]=a1.y; a[6]=a1.z; a[7]=a1.w;
      bv[0]=b0.x; bv[1]=b0.y; bv[2]=b0.z; bv[3]=b0.w;
      #pragma unroll
      for (int im = 0; im < 8; ++im)
        #pragma unroll
        for (int in = 0; in < 4; ++in)
          acc[im][in] = fmaf(a[im], bv[in], acc[im][in]);
    }
  }
  #pragma unroll
  for (int im = 0; im < 8; ++im) {
    float4 o; o.x = acc[im][0]; o.y = acc[im][1]; o.z = acc[im][2]; o.w = acc[im][3];
    *(float4*)&Y[(size_t)(m0 + mi*8 + im)*320 + n0 + ni*4] = o;
  }
}

// ---------------- k2: per-token postprocess
// k=l2norm(y0), v=y1, q=l2norm(y2), qk=dot(q,k), u_slow from imp-logit,
// nu = gelu(v@nm_w1^T + b1)@nm_w2^T + b2, pwt = softmax(y4[3])
__global__ __launch_bounds__(256) void post_kernel(
    const float* __restrict__ Y,
    const float* __restrict__ nm_w1, const float* __restrict__ nm_b1,
    const float* __restrict__ nm_w2, const float* __restrict__ nm_b2,
    const float* __restrict__ ir_b1, const float* __restrict__ ir_w2,
    const float* __restrict__ ir_b2, const float* __restrict__ sap,
    float* __restrict__ K, float* __restrict__ V, float* __restrict__ Q,
    float* __restrict__ NU, float* __restrict__ PW,
    float* __restrict__ QKD, float* __restrict__ BS) {
  __shared__ float w1s[128*65];   // padded stride 65: bank = (l+c)%32, conflict-free
  __shared__ float w2s[64*129];
  __shared__ float vbuf[4][64];
  __shared__ float h1buf[4][128];
  const int tid = threadIdx.x, wid = tid >> 6, l = tid & 63;
  for (int i = tid; i < 128*64; i += 256) w1s[(i>>6)*65 + (i&63)]  = nm_w1[i];
  for (int i = tid; i < 64*128; i += 256) w2s[(i>>7)*129 + (i&127)] = nm_w2[i];
  __syncthreads();
  const float sa   = *sap;
  const float b1a  = nm_b1[l], b1b = nm_b1[64+l], b2l = nm_b2[l];
  const float irb1 = ir_b1[l], irw2 = ir_w2[l],  irb2 = ir_b2[0];
  for (int r = 0; r < 4; ++r) {
    const int tok = blockIdx.x*16 + r*4 + wid;
    const float* yr = Y + (size_t)tok*320;
    float kr = yr[l], vr = yr[64+l], qr = yr[128+l], hr = yr[192+l];
    float rk = 1.f / fmaxf(sqrtf(wsum(kr*kr)), 1e-12f);
    float rq = 1.f / fmaxf(sqrtf(wsum(qr*qr)), 1e-12f);
    float kn = kr*rk, qn = qr*rq;
    float qk = wsum(kn*qn);
    float g  = gelu_exact(hr + irb1);
    float logit = wsum(g*irw2) + irb2;
    float imp = 1.f/(1.f+expf(-logit));
    float bs  = (imp > 0.5f) ? (1.f - sa) : 0.f;   // (1-slow_alpha)*u_slow
    K[(size_t)tok*64+l] = kn; V[(size_t)tok*64+l] = vr; Q[(size_t)tok*64+l] = qn;
    vbuf[wid][l] = vr;
    __syncthreads();
    float h1a = b1a, h1b = b1b;
    #pragma unroll 8
    for (int c = 0; c < 64; ++c) {
      float vv = vbuf[wid][c];
      h1a = fmaf(w1s[l*65 + c], vv, h1a);
      h1b = fmaf(w1s[(64+l)*65 + c], vv, h1b);
    }
    h1buf[wid][l]    = gelu_exact(h1a);
    h1buf[wid][64+l] = gelu_exact(h1b);
    __syncthreads();
    float nu = b2l;
    #pragma unroll 8
    for (int j = 0; j < 128; ++j) nu = fmaf(w2s[l*129 + j], h1buf[wid][j], nu);
    NU[(size_t)tok*64+l] = nu;
    float p0 = yr[256], p1 = yr[257], p2 = yr[258];
    float mx = fmaxf(p0, fmaxf(p1, p2));
    float e0 = expf(p0-mx), e1 = expf(p1-mx), e2 = expf(p2-mx);
    float inv = 1.f/(e0+e1+e2);
    if (l == 0)      { PW[(size_t)tok*3]   = e0*inv; QKD[tok] = qk; BS[tok] = bs; }
    else if (l == 1)   PW[(size_t)tok*3+1] = e1*inv;
    else if (l == 2)   PW[(size_t)tok*3+2] = e2*inv;
    __syncthreads();
  }
}

// ---------------- k3: the sequential scan, column-parallel.
// One wave per (b, v). Lane l holds fH[l][v], sH[l][v]. Per step: 4 butterfly
// dot-reduces; emits OBASE = p0*qf_new + p1*qs_new and e = (v - pred)^2.
__global__ __launch_bounds__(64) void scan_kernel(
    const float* __restrict__ K, const float* __restrict__ Q,
    const float* __restrict__ V, const float* __restrict__ QKD,
    const float* __restrict__ BS, const float* __restrict__ PW,
    const float* __restrict__ fap, const float* __restrict__ sap,
    float* __restrict__ OBASE, float* __restrict__ E) {
  const int b = blockIdx.x >> 6;
  const int v = blockIdx.x & 63;
  const int l = threadIdx.x;
  const float fa = *fap, sa = *sap;
  const float omfa = 1.f - fa;
  const size_t base = (size_t)b * SS * 64;
  const float* Kb  = K + base;
  const float* Qb  = Q + base;
  const float* Vb  = V + base + v;
  const float* QKb = QKD + (size_t)b * SS;
  const float* BSb = BS  + (size_t)b * SS;
  const float* PWb = PW  + (size_t)b * SS * 3;
  float fH = 0.f, sH = 0.f;
  float kc = Kb[l], qc = Qb[l];
  float vc = Vb[0], qkc = QKb[0], bsc = BSb[0], p0c = PWb[0], p1c = PWb[1];
  for (int t = 0; t < SS; ++t) {
    const int tn = (t + 1 < SS) ? (t + 1) : t;   // branch-free prefetch
    float kn  = Kb[(size_t)tn*64 + l];
    float qn  = Qb[(size_t)tn*64 + l];
    float vn  = Vb[(size_t)tn*64];
    float qkn = QKb[tn], bsn = BSb[tn];
    float p0n = PWb[tn*3], p1n = PWb[tn*3+1];
    // 4 independent reduces; compiler interleaves the DPP chains
    float pf  = wsum(kc*fH);
    float pq  = wsum(qc*fH);
    float ps  = wsum(kc*sH);
    float pqs = wsum(qc*sH);
    float ef = vc - pf, es = vc - ps;
    float pd = vc - 0.5f*(pq + pqs);
    float e  = pd*pd;
    fH = fmaf(omfa*kc, ef, fa*fH);
    sH = fmaf(bsc*kc, es, sa*sH);
    float qfn = fmaf(omfa*qkc, ef, fa*pq);
    float qsn = fmaf(bsc*qkc,  es, sa*pqs);
    float ob = p0c*qfn + p1c*qsn;
    size_t o = ((size_t)b*SS + t)*64 + v;
    if (l == 0)       OBASE[o] = ob;
    else if (l == 32) E[o] = e;
    kc=kn; qc=qn; vc=vn; qkc=qkn; bsc=bsn; p0c=p0n; p1c=p1n;
  }
}

// ---------------- k4: err reduce -> ns-gate coefficient c = 0.1*u_neu
__global__ __launch_bounds__(256) void err_kernel(
    const float* __restrict__ E, float* __restrict__ CNS) {
  int row = blockIdx.x*4 + (threadIdx.x >> 6);
  int l = threadIdx.x & 63;
  float s = wsum(E[(size_t)row*64 + l]);
  if (l == 0) {
    float z = s / (1.0f + 1e-6f);          // TEMP + 1e-6
    float sg = 1.f/(1.f+expf(-z));
    CNS[row] = (sg > 0.7f) ? 0.1f : 0.f;
  }
}

// ---------------- k5: ns scan + o assembly, software-pipelined
#define BW 16
__device__ __forceinline__ void loadw(int b, int t0, int v,
    const float* __restrict__ CNS, const float* __restrict__ NU,
    const float* __restrict__ OBASE, const float* __restrict__ PW,
    float* c, float* nu, float* ob, float* p2) {
  #pragma unroll
  for (int i = 0; i < BW; ++i) {
    size_t bt = (size_t)b*SS + (t0 + i);
    c[i]  = CNS[bt];
    nu[i] = NU[bt*64 + v];
    ob[i] = OBASE[bt*64 + v];
    p2[i] = PW[bt*3 + 2];
  }
}
__device__ __forceinline__ float procw(int b, int t0, int v, float ns,
    const float* c, const float* nu, const float* ob, const float* p2,
    float* __restrict__ OB) {
  #pragma unroll
  for (int i = 0; i < BW; ++i) {
    float cn = c[i]*nu[i];
    float a  = 1.f - c[i];
    ns = fmaf(a, ns, cn);                 // ns = (1-c)*ns + c*nu
    float o = fmaf(p2[i], ns, ob[i]);
    OB[((size_t)b*SS + (t0+i))*64 + v] = o;
  }
  return ns;
}
__global__ __launch_bounds__(64) void nsout_kernel(
    const float* __restrict__ CNS, const float* __restrict__ NU,
    const float* __restrict__ OBASE, const float* __restrict__ PW,
    float* __restrict__ OB) {
  const int b = blockIdx.x, v = threadIdx.x;
  float cA[BW],nA[BW],oA[BW],pA[BW], cB[BW],nB[BW],oB[BW],pB[BW];
  loadw(b, 0, v, CNS, NU, OBASE, PW, cA, nA, oA, pA);
  float ns = 0.f;
  for (int t0 = 0; t0 < SS; t0 += 2*BW) {
    int tB = t0 + BW;
    loadw(b, tB, v, CNS, NU, OBASE, PW, cB, nB, oB, pB);
    ns = procw(b, t0, v, ns, cA, nA, oA, pA, OB);
    int tA2 = t0 + 2*BW; if (tA2 > SS - BW) tA2 = SS - BW;  // clamped (redundant ok)
    loadw(b, tA2, v, CNS, NU, OBASE, PW, cA, nA, oA, pA);
    ns = procw(b, tB, v, ns, cB, nB, oB, pB, OB);
  }
}

// ---------------- k6: fused RMSNorm + out = normed @ Wo^T
// Mtile=64, Ntile=128, K=64 in one shot.
__global__ __launch_bounds__(256) void out_gemm(
    const float* __restrict__ OB, const float* __restrict__ Wo,
    const float* __restrict__ normw, float* __restrict__ out) {
  __shared__ float As[64*64];    // [k][m]
  __shared__ float Bs[64*128];   // [k][n]
  const int t  = threadIdx.x;
  const int m0 = blockIdx.y * 64;
  const int n0 = blockIdx.x * 128;
  {   // stage A with fused RMSNorm * norm_w
    int r = t >> 2, q4 = t & 3;
    const float* src = OB + (size_t)(m0 + r)*64 + q4*16;
    float4 x0 = ld4(src), x1 = ld4(src+4), x2 = ld4(src+8), x3 = ld4(src+12);
    float ss = x0.x*x0.x+x0.y*x0.y+x0.z*x0.z+x0.w*x0.w
             + x1.x*x1.x+x1.y*x1.y+x1.z*x1.z+x1.w*x1.w
             + x2.x*x2.x+x2.y*x2.y+x2.z*x2.z+x2.w*x2.w
             + x3.x*x3.x+x3.y*x3.y+x3.z*x3.z+x3.w*x3.w;
    ss += __shfl_xor(ss, 1, 64);
    ss += __shfl_xor(ss, 2, 64);
    float rms = rsqrtf(ss * (1.f/64.f) + 1e-6f);
    const float* nw = normw + q4*16;
    float4 w0 = ld4(nw), w1 = ld4(nw+4), w2 = ld4(nw+8), w3 = ld4(nw+12);
    int kbase = q4*16;
    As[(kbase+ 0)*64+r]=x0.x*rms*w0.x; As[(kbase+ 1)*64+r]=x0.y*rms*w0.y;
    As[(kbase+ 2)*64+r]=x0.z*rms*w0.z; As[(kbase+ 3)*64+r]=x0.w*rms*w0.w;
    As[(kbase+ 4)*64+r]=x1.x*rms*w1.x; As[(kbase+ 5)*64+r]=x1.y*rms*w1.y;
    As[(kbase+ 6)*64+r]=x1.z*rms*w1.z; As[(kbase+ 7)*64+r]=x1.w*rms*w1.w;
    As[(kbase+ 8)*64+r]=x2.x*rms*w2.x; As[(kbase+ 9)*64+r]=x2.y*rms*w2.y;
    As[(kbase+10)*64+r]=x2.z*rms*w2.z; As[(kbase+11)*64+r]=x2.w*rms*w2.w;
    As[(kbase+12)*64+r]=x3.x*rms*w3.x; As[(kbase+13)*64+r]=x3.y*rms*w3.y;
    As[(kbase+14)*64+r]=x3.z*rms*w3.z; As[(kbase+15)*64+r]=x3.w*rms*w3.w;
  }
  {   // stage B (Wo rows n0..n0+127), transposed to [k][n]
    int rw = t >> 1, half = t & 1;
    const float* src = Wo + (size_t)(n0 + rw)*64 + half*32;
    #pragma unroll
    for (int j = 0; j < 8; ++j) {
      float4 w = ld4(src + j*4);
      int k = half*32 + j*4;
      Bs[(k+0)*128+rw] = w.x; Bs[(k+1)*128+rw] = w.y;
      Bs[(k+2)*128+rw] = w.z; Bs[(k+3)*128+rw] = w.w;
    }
  }
  __syncthreads();
  const int mi = t >> 5, ni = t & 31;
  float acc[8][4];
  #pragma unroll
  for (int i = 0; i < 8; ++i)
    #pragma unroll
    for (int j = 0; j < 4; ++j) acc[i][j] = 0.f;
  #pragma unroll 8
  for (int k = 0; k < 64; ++k) {
    float a[8], bv[4];
    float4 a0 = *(const float4*)&As[k*64 + mi*8];
    float4 a1 = *(const float4*)&As[k*64 + mi*8 + 4];
    float4 b0 = *(const float4*)&Bs[k*128 + ni*4];
    a[0]=a0.x; a[1]=a0.y; a[2]=a0.z; a[3]=a0.w;
    a[4]=a1.x; a[5]=a1.y; a[6]=a1.z; a[7]=a1.w;
    bv[0]=b0.x; bv[1]=b0.y; bv[2]=b0.z; bv[3]=b0.w;
    #pragma unroll
    for (int im = 0; im < 8; ++im)
      #pragma unroll
      for (int in = 0; in < 4; ++in)
        acc[im][in] = fmaf(a[im], bv[in], acc[im][in]);
  }
  #pragma unroll
  for (int im = 0; im < 8; ++im) {
    float4 o; o.x=acc[im][0]; o.y=acc[im][1]; o.z=acc[im][2]; o.w=acc[im][3];
    *(float4*)&out[(size_t)(m0 + mi*8 + im)*1024 + n0 + ni*4] = o;
  }
}

// ---------------- launcher ----------------
extern "C" void kernel_launch(void* const* d_in, const int* in_sizes, int n_in,
                              void* d_out, int out_size, void* d_ws, size_t ws_size,
                              hipStream_t stream) {
  const float* x     = (const float*)d_in[0];
  const float* Wk    = (const float*)d_in[1];
  const float* Wv    = (const float*)d_in[2];
  const float* Wq    = (const float*)d_in[3];
  const float* fap   = (const float*)d_in[4];
  const float* sap   = (const float*)d_in[5];
  const float* nm_w1 = (const float*)d_in[6];
  const float* nm_b1 = (const float*)d_in[7];
  const float* nm_w2 = (const float*)d_in[8];
  const float* nm_b2 = (const float*)d_in[9];
  const float* ir_w1 = (const float*)d_in[10];
  const float* ir_b1 = (const float*)d_in[11];
  const float* ir_w2 = (const float*)d_in[12];
  const float* ir_b2 = (const float*)d_in[13];
  const float* pw    = (const float*)d_in[14];
  const float* Wo    = (const float*)d_in[15];
  const float* normw = (const float*)d_in[16];
  float* out = (float*)d_out;
  float* ws  = (float*)d_ws;

  // workspace layout (floats)
  const size_t oW    = 0;
  const size_t oY    = oW  + (size_t)320*1024;        // Wcat
  const size_t oK    = oY  + (size_t)MM*320;          // Y (reused below)
  const size_t oV    = oK  + (size_t)MM*64;
  const size_t oQ    = oV  + (size_t)MM*64;
  const size_t oNU   = oQ  + (size_t)MM*64;
  const size_t oPW   = oNU + (size_t)MM*64;
  const size_t oQKD  = oPW + (size_t)MM*3;
  const size_t oBS   = oQKD + MM;
  const size_t oCNS  = oBS  + MM;
  const size_t oOB   = oCNS + MM;
  // Y region reused after post_kernel:
  const size_t oOBASE = oY;
  const size_t oE     = oY + (size_t)MM*64;

  pack_w<<<1280, 256, 0, stream>>>(Wk, Wv, Wq, ir_w1, pw, ws + oW);
  gemm1<<<dim3(128, 5), 256, 0, stream>>>(x, ws + oW, ws + oY);
  post_kernel<<<1024, 256, 0, stream>>>(ws + oY, nm_w1, nm_b1, nm_w2, nm_b2,
                                        ir_b1, ir_w2, ir_b2, sap,
                                        ws + oK, ws + oV, ws + oQ, ws + oNU,
                                        ws + oPW, ws + oQKD, ws + oBS);
  scan_kernel<<<512, 64, 0, stream>>>(ws + oK, ws + oQ, ws + oV, ws + oQKD,
                                      ws + oBS, ws + oPW, fap, sap,
                                      ws + oOBASE, ws + oE);
  err_kernel<<<4096, 256, 0, stream>>>(ws + oE, ws + oCNS);
  nsout_kernel<<<8, 64, 0, stream>>>(ws + oCNS, ws + oNU, ws + oOBASE,
                                     ws + oPW, ws + oOB);
  out_gemm<<<dim3(8, 256), 256, 0, stream>>>(ws + oOB, Wo, normw, out);
}

// Round 2
// 1278.085 us; speedup vs baseline: 1.0960x; 1.0960x over previous
//
#include <hip/hip_runtime.h>
#include <hip/hip_bf16.h>
#include <math.h>

// Problem constants (match reference)
#define BB 8
#define SS 2048
#define DD 1024
#define DS 64
#define MM (BB*SS)   // 16384

// ---------------- helpers ----------------

__device__ __forceinline__ float4 ld4(const float* p) { return *(const float4*)p; }

template<int CTRL>
__device__ __forceinline__ float dppadd(float x) {
  int v = __builtin_amdgcn_update_dpp(0, __float_as_int(x), CTRL, 0xf, 0xf, true);
  return x + __int_as_float(v);
}

// full 64-lane butterfly sum; result valid in all lanes
__device__ __forceinline__ float wsum(float x) {
  x = dppadd<0xB1>(x);   // quad_perm [1,0,3,2]  (xor 1)
  x = dppadd<0x4E>(x);   // quad_perm [2,3,0,1]  (xor 2)
  x = dppadd<0x141>(x);  // row_half_mirror      (completes 8-group)
  x = dppadd<0x140>(x);  // row_mirror           (completes 16-group)
  x += __shfl_xor(x, 16, 64);
  x += __shfl_xor(x, 32, 64);
  return x;
}

__device__ __forceinline__ float gelu_exact(float x) {
  return 0.5f * x * (1.f + erff(x * 0.7071067811865476f));
}

// ---------------- k0: pack weights [Wk;Wv;Wq;ir_w1;pw;0-pad] -> Wcat[320][1024]
__global__ __launch_bounds__(256) void pack_w(
    const float* __restrict__ Wk, const float* __restrict__ Wv,
    const float* __restrict__ Wq, const float* __restrict__ ir_w1,
    const float* __restrict__ pw, float* __restrict__ Wcat) {
  int idx = blockIdx.x * 256 + threadIdx.x;   // 320*1024 total
  int r = idx >> 10, c = idx & 1023;
  float val = 0.f;
  if (r < 64)       val = Wk[r*1024 + c];
  else if (r < 128) val = Wv[(r-64)*1024 + c];
  else if (r < 192) val = Wq[(r-128)*1024 + c];
  else if (r < 256) val = ir_w1[(r-192)*1024 + c];
  else if (r < 259) val = pw[(r-256)*1024 + c];
  Wcat[idx] = val;
}

// ---------------- k1: Y[16384][320] = X[16384][1024] @ Wcat[320][1024]^T
__global__ __launch_bounds__(256) void gemm1(
    const float* __restrict__ X, const float* __restrict__ Wcat,
    float* __restrict__ Y) {
  __shared__ float As[32*128];   // [k][m]
  __shared__ float Bs[32*64];    // [k][n]
  const int t  = threadIdx.x;
  const int m0 = blockIdx.x * 128;
  const int n0 = blockIdx.y * 64;
  const int mi = t >> 4, ni = t & 15;
  const int rA = t >> 1, hA = t & 1;
  const int rB = t >> 2, qB = t & 3;
  float acc[8][4];
  #pragma unroll
  for (int i = 0; i < 8; ++i)
    #pragma unroll
    for (int j = 0; j < 4; ++j) acc[i][j] = 0.f;

  for (int k0 = 0; k0 < 1024; k0 += 32) {
    __syncthreads();
    {
      const float* src = X + (size_t)(m0 + rA)*1024 + k0 + hA*16;
      #pragma unroll
      for (int jj = 0; jj < 4; ++jj) {
        float4 xv = ld4(src + jj*4);
        int kk = hA*16 + jj*4;
        As[(kk+0)*128 + rA] = xv.x; As[(kk+1)*128 + rA] = xv.y;
        As[(kk+2)*128 + rA] = xv.z; As[(kk+3)*128 + rA] = xv.w;
      }
      const float* srcB = Wcat + (size_t)(n0 + rB)*1024 + k0 + qB*8;
      #pragma unroll
      for (int jj = 0; jj < 2; ++jj) {
        float4 bv = ld4(srcB + jj*4);
        int kb = qB*8 + jj*4;
        Bs[(kb+0)*64 + rB] = bv.x; Bs[(kb+1)*64 + rB] = bv.y;
        Bs[(kb+2)*64 + rB] = bv.z; Bs[(kb+3)*64 + rB] = bv.w;
      }
    }
    __syncthreads();
    #pragma unroll
    for (int kk = 0; kk < 32; ++kk) {
      float a[8], bv[4];
      float4 a0 = *(const float4*)&As[kk*128 + mi*8];
      float4 a1 = *(const float4*)&As[kk*128 + mi*8 + 4];
      float4 b0 = *(const float4*)&Bs[kk*64 + ni*4];
      a[0]=a0.x; a[1]=a0.y; a[2]=a0.z; a[3]=a0.w;
      a[4]=a1.x; a[5]=a1.y; a[6]=a1.z; a[7]=a1.w;
      bv[0]=b0.x; bv[1]=b0.y; bv[2]=b0.z; bv[3]=b0.w;
      #pragma unroll
      for (int im = 0; im < 8; ++im)
        #pragma unroll
        for (int in = 0; in < 4; ++in)
          acc[im][in] = fmaf(a[im], bv[in], acc[im][in]);
    }
  }
  #pragma unroll
  for (int im = 0; im < 8; ++im) {
    float4 o; o.x = acc[im][0]; o.y = acc[im][1]; o.z = acc[im][2]; o.w = acc[im][3];
    *(float4*)&Y[(size_t)(m0 + mi*8 + im)*320 + n0 + ni*4] = o;
  }
}

// ---------------- k2: per-token postprocess
// Emits K, V, Q, NU, PW (p2 for nsout) and packed SCL = {qk, bs, p0, p1}.
__global__ __launch_bounds__(256) void post_kernel(
    const float* __restrict__ Y,
    const float* __restrict__ nm_w1, const float* __restrict__ nm_b1,
    const float* __restrict__ nm_w2, const float* __restrict__ nm_b2,
    const float* __restrict__ ir_b1, const float* __restrict__ ir_w2,
    const float* __restrict__ ir_b2, const float* __restrict__ sap,
    float* __restrict__ K, float* __restrict__ V, float* __restrict__ Q,
    float* __restrict__ NU, float* __restrict__ PW,
    float* __restrict__ SCL) {
  __shared__ float w1s[128*65];
  __shared__ float w2s[64*129];
  __shared__ float vbuf[4][64];
  __shared__ float h1buf[4][128];
  const int tid = threadIdx.x, wid = tid >> 6, l = tid & 63;
  for (int i = tid; i < 128*64; i += 256) w1s[(i>>6)*65 + (i&63)]  = nm_w1[i];
  for (int i = tid; i < 64*128; i += 256) w2s[(i>>7)*129 + (i&127)] = nm_w2[i];
  __syncthreads();
  const float sa   = *sap;
  const float b1a  = nm_b1[l], b1b = nm_b1[64+l], b2l = nm_b2[l];
  const float irb1 = ir_b1[l], irw2 = ir_w2[l],  irb2 = ir_b2[0];
  for (int r = 0; r < 4; ++r) {
    const int tok = blockIdx.x*16 + r*4 + wid;
    const float* yr = Y + (size_t)tok*320;
    float kr = yr[l], vr = yr[64+l], qr = yr[128+l], hr = yr[192+l];
    float rk = 1.f / fmaxf(sqrtf(wsum(kr*kr)), 1e-12f);
    float rq = 1.f / fmaxf(sqrtf(wsum(qr*qr)), 1e-12f);
    float kn = kr*rk, qn = qr*rq;
    float qk = wsum(kn*qn);
    float g  = gelu_exact(hr + irb1);
    float logit = wsum(g*irw2) + irb2;
    float imp = 1.f/(1.f+expf(-logit));
    float bs  = (imp > 0.5f) ? (1.f - sa) : 0.f;   // (1-slow_alpha)*u_slow
    K[(size_t)tok*64+l] = kn; V[(size_t)tok*64+l] = vr; Q[(size_t)tok*64+l] = qn;
    vbuf[wid][l] = vr;
    __syncthreads();
    float h1a = b1a, h1b = b1b;
    #pragma unroll 8
    for (int c = 0; c < 64; ++c) {
      float vv = vbuf[wid][c];
      h1a = fmaf(w1s[l*65 + c], vv, h1a);
      h1b = fmaf(w1s[(64+l)*65 + c], vv, h1b);
    }
    h1buf[wid][l]    = gelu_exact(h1a);
    h1buf[wid][64+l] = gelu_exact(h1b);
    __syncthreads();
    float nu = b2l;
    #pragma unroll 8
    for (int j = 0; j < 128; ++j) nu = fmaf(w2s[l*129 + j], h1buf[wid][j], nu);
    NU[(size_t)tok*64+l] = nu;
    float p0 = yr[256], p1 = yr[257], p2 = yr[258];
    float mx = fmaxf(p0, fmaxf(p1, p2));
    float e0 = expf(p0-mx), e1 = expf(p1-mx), e2 = expf(p2-mx);
    float inv = 1.f/(e0+e1+e2);
    if (l == 0) {
      PW[(size_t)tok*3]   = e0*inv;
      float4 s; s.x = qk; s.y = bs; s.z = e0*inv; s.w = e1*inv;
      *(float4*)&SCL[(size_t)tok*4] = s;
    }
    else if (l == 1)   PW[(size_t)tok*3+1] = e1*inv;
    else if (l == 2)   PW[(size_t)tok*3+2] = e2*inv;
    __syncthreads();
  }
}

// ---------------- k3: sequential scan, column-parallel, PF-deep prefetch.
// One wave per (b, v). Lane l holds fH[l][v], sH[l][v].
#define PF 8
__global__ __launch_bounds__(64) void scan_kernel(
    const float* __restrict__ K, const float* __restrict__ Q,
    const float* __restrict__ V, const float* __restrict__ SCL,
    const float* __restrict__ fap, const float* __restrict__ sap,
    float* __restrict__ OBASE, float* __restrict__ E) {
  const int b = blockIdx.x >> 6;
  const int v = blockIdx.x & 63;
  const int l = threadIdx.x;
  const float fa = *fap, sa = *sap;
  const float omfa = 1.f - fa;
  const size_t base = (size_t)b * SS * 64;
  const float* Kb  = K + base;
  const float* Qb  = Q + base;
  const float* Vb  = V + base + v;
  const float* Sb  = SCL + (size_t)b * SS * 4;
  float fH = 0.f, sH = 0.f;
  float  kb_[PF], qb_[PF], vb_[PF];
  float4 sb_[PF];
  #pragma unroll
  for (int i = 0; i < PF; ++i) {
    kb_[i] = Kb[(size_t)i*64 + l];
    qb_[i] = Qb[(size_t)i*64 + l];
    vb_[i] = Vb[(size_t)i*64];
    sb_[i] = *(const float4*)&Sb[(size_t)i*4];
  }
  for (int t0 = 0; t0 < SS; t0 += PF) {
    #pragma unroll
    for (int i = 0; i < PF; ++i) {
      const int t = t0 + i;
      const float kc = kb_[i], qc = qb_[i], vc = vb_[i];
      const float qkc = sb_[i].x, bsc = sb_[i].y, p0c = sb_[i].z, p1c = sb_[i].w;
      // issue loads for t+PF (clamped; tail values never consumed)
      const int tl = (t + PF < SS) ? (t + PF) : (SS - 1);
      kb_[i] = Kb[(size_t)tl*64 + l];
      qb_[i] = Qb[(size_t)tl*64 + l];
      vb_[i] = Vb[(size_t)tl*64];
      sb_[i] = *(const float4*)&Sb[(size_t)tl*4];
      // 4 independent butterfly reduces
      float pf  = wsum(kc*fH);
      float pq  = wsum(qc*fH);
      float ps  = wsum(kc*sH);
      float pqs = wsum(qc*sH);
      float ef = vc - pf, es = vc - ps;
      float pd = vc - 0.5f*(pq + pqs);
      float e  = pd*pd;
      fH = fmaf(omfa*kc, ef, fa*fH);
      sH = fmaf(bsc*kc, es, sa*sH);
      float qfn = fmaf(omfa*qkc, ef, fa*pq);
      float qsn = fmaf(bsc*qkc,  es, sa*pqs);
      float ob = p0c*qfn + p1c*qsn;
      size_t o = ((size_t)b*SS + t)*64 + v;
      if (l == 0)       OBASE[o] = ob;
      else if (l == 32) E[o] = e;
    }
  }
}

// ---------------- k4: err reduce -> ns-gate coefficient c = 0.1*u_neu
__global__ __launch_bounds__(256) void err_kernel(
    const float* __restrict__ E, float* __restrict__ CNS) {
  int row = blockIdx.x*4 + (threadIdx.x >> 6);
  int l = threadIdx.x & 63;
  float s = wsum(E[(size_t)row*64 + l]);
  if (l == 0) {
    float z = s / (1.0f + 1e-6f);          // TEMP + 1e-6
    float sg = 1.f/(1.f+expf(-z));
    CNS[row] = (sg > 0.7f) ? 0.1f : 0.f;
  }
}

// ---------------- k5: ns scan + o assembly, software-pipelined
#define BW 16
__device__ __forceinline__ void loadw(int b, int t0, int v,
    const float* __restrict__ CNS, const float* __restrict__ NU,
    const float* __restrict__ OBASE, const float* __restrict__ PW,
    float* c, float* nu, float* ob, float* p2) {
  #pragma unroll
  for (int i = 0; i < BW; ++i) {
    size_t bt = (size_t)b*SS + (t0 + i);
    c[i]  = CNS[bt];
    nu[i] = NU[bt*64 + v];
    ob[i] = OBASE[bt*64 + v];
    p2[i] = PW[bt*3 + 2];
  }
}
__device__ __forceinline__ float procw(int b, int t0, int v, float ns,
    const float* c, const float* nu, const float* ob, const float* p2,
    float* __restrict__ OB) {
  #pragma unroll
  for (int i = 0; i < BW; ++i) {
    float cn = c[i]*nu[i];
    float a  = 1.f - c[i];
    ns = fmaf(a, ns, cn);                 // ns = (1-c)*ns + c*nu
    float o = fmaf(p2[i], ns, ob[i]);
    OB[((size_t)b*SS + (t0+i))*64 + v] = o;
  }
  return ns;
}
__global__ __launch_bounds__(64) void nsout_kernel(
    const float* __restrict__ CNS, const float* __restrict__ NU,
    const float* __restrict__ OBASE, const float* __restrict__ PW,
    float* __restrict__ OB) {
  const int b = blockIdx.x, v = threadIdx.x;
  float cA[BW],nA[BW],oA[BW],pA[BW], cB[BW],nB[BW],oB[BW],pB[BW];
  loadw(b, 0, v, CNS, NU, OBASE, PW, cA, nA, oA, pA);
  float ns = 0.f;
  for (int t0 = 0; t0 < SS; t0 += 2*BW) {
    int tB = t0 + BW;
    loadw(b, tB, v, CNS, NU, OBASE, PW, cB, nB, oB, pB);
    ns = procw(b, t0, v, ns, cA, nA, oA, pA, OB);
    int tA2 = t0 + 2*BW; if (tA2 > SS - BW) tA2 = SS - BW;
    loadw(b, tA2, v, CNS, NU, OBASE, PW, cA, nA, oA, pA);
    ns = procw(b, tB, v, ns, cB, nB, oB, pB, OB);
  }
}

// ---------------- k6: fused RMSNorm + out = normed @ Wo^T
__global__ __launch_bounds__(256) void out_gemm(
    const float* __restrict__ OB, const float* __restrict__ Wo,
    const float* __restrict__ normw, float* __restrict__ out) {
  __shared__ float As[64*64];    // [k][m]
  __shared__ float Bs[64*128];   // [k][n]
  const int t  = threadIdx.x;
  const int m0 = blockIdx.y * 64;
  const int n0 = blockIdx.x * 128;
  {
    int r = t >> 2, q4 = t & 3;
    const float* src = OB + (size_t)(m0 + r)*64 + q4*16;
    float4 x0 = ld4(src), x1 = ld4(src+4), x2 = ld4(src+8), x3 = ld4(src+12);
    float ss = x0.x*x0.x+x0.y*x0.y+x0.z*x0.z+x0.w*x0.w
             + x1.x*x1.x+x1.y*x1.y+x1.z*x1.z+x1.w*x1.w
             + x2.x*x2.x+x2.y*x2.y+x2.z*x2.z+x2.w*x2.w
             + x3.x*x3.x+x3.y*x3.y+x3.z*x3.z+x3.w*x3.w;
    ss += __shfl_xor(ss, 1, 64);
    ss += __shfl_xor(ss, 2, 64);
    float rms = rsqrtf(ss * (1.f/64.f) + 1e-6f);
    const float* nw = normw + q4*16;
    float4 w0 = ld4(nw), w1 = ld4(nw+4), w2 = ld4(nw+8), w3 = ld4(nw+12);
    int kbase = q4*16;
    As[(kbase+ 0)*64+r]=x0.x*rms*w0.x; As[(kbase+ 1)*64+r]=x0.y*rms*w0.y;
    As[(kbase+ 2)*64+r]=x0.z*rms*w0.z; As[(kbase+ 3)*64+r]=x0.w*rms*w0.w;
    As[(kbase+ 4)*64+r]=x1.x*rms*w1.x; As[(kbase+ 5)*64+r]=x1.y*rms*w1.y;
    As[(kbase+ 6)*64+r]=x1.z*rms*w1.z; As[(kbase+ 7)*64+r]=x1.w*rms*w1.w;
    As[(kbase+ 8)*64+r]=x2.x*rms*w2.x; As[(kbase+ 9)*64+r]=x2.y*rms*w2.y;
    As[(kbase+10)*64+r]=x2.z*rms*w2.z; As[(kbase+11)*64+r]=x2.w*rms*w2.w;
    As[(kbase+12)*64+r]=x3.x*rms*w3.x; As[(kbase+13)*64+r]=x3.y*rms*w3.y;
    As[(kbase+14)*64+r]=x3.z*rms*w3.z; As[(kbase+15)*64+r]=x3.w*rms*w3.w;
  }
  {
    int rw = t >> 1, half = t & 1;
    const float* src = Wo + (size_t)(n0 + rw)*64 + half*32;
    #pragma unroll
    for (int j = 0; j < 8; ++j) {
      float4 w = ld4(src + j*4);
      int k = half*32 + j*4;
      Bs[(k+0)*128+rw] = w.x; Bs[(k+1)*128+rw] = w.y;
      Bs[(k+2)*128+rw] = w.z; Bs[(k+3)*128+rw] = w.w;
    }
  }
  __syncthreads();
  const int mi = t >> 5, ni = t & 31;
  float acc[8][4];
  #pragma unroll
  for (int i = 0; i < 8; ++i)
    #pragma unroll
    for (int j = 0; j < 4; ++j) acc[i][j] = 0.f;
  #pragma unroll 8
  for (int k = 0; k < 64; ++k) {
    float a[8], bv[4];
    float4 a0 = *(const float4*)&As[k*64 + mi*8];
    float4 a1 = *(const float4*)&As[k*64 + mi*8 + 4];
    float4 b0 = *(const float4*)&Bs[k*128 + ni*4];
    a[0]=a0.x; a[1]=a0.y; a[2]=a0.z; a[3]=a0.w;
    a[4]=a1.x; a[5]=a1.y; a[6]=a1.z; a[7]=a1.w;
    bv[0]=b0.x; bv[1]=b0.y; bv[2]=b0.z; bv[3]=b0.w;
    #pragma unroll
    for (int im = 0; im < 8; ++im)
      #pragma unroll
      for (int in = 0; in < 4; ++in)
        acc[im][in] = fmaf(a[im], bv[in], acc[im][in]);
  }
  #pragma unroll
  for (int im = 0; im < 8; ++im) {
    float4 o; o.x=acc[im][0]; o.y=acc[im][1]; o.z=acc[im][2]; o.w=acc[im][3];
    *(float4*)&out[(size_t)(m0 + mi*8 + im)*1024 + n0 + ni*4] = o;
  }
}

// ---------------- launcher ----------------
extern "C" void kernel_launch(void* const* d_in, const int* in_sizes, int n_in,
                              void* d_out, int out_size, void* d_ws, size_t ws_size,
                              hipStream_t stream) {
  const float* x     = (const float*)d_in[0];
  const float* Wk    = (const float*)d_in[1];
  const float* Wv    = (const float*)d_in[2];
  const float* Wq    = (const float*)d_in[3];
  const float* fap   = (const float*)d_in[4];
  const float* sap   = (const float*)d_in[5];
  const float* nm_w1 = (const float*)d_in[6];
  const float* nm_b1 = (const float*)d_in[7];
  const float* nm_w2 = (const float*)d_in[8];
  const float* nm_b2 = (const float*)d_in[9];
  const float* ir_w1 = (const float*)d_in[10];
  const float* ir_b1 = (const float*)d_in[11];
  const float* ir_w2 = (const float*)d_in[12];
  const float* ir_b2 = (const float*)d_in[13];
  const float* pw    = (const float*)d_in[14];
  const float* Wo    = (const float*)d_in[15];
  const float* normw = (const float*)d_in[16];
  float* out = (float*)d_out;
  float* ws  = (float*)d_ws;

  // workspace layout (floats)
  const size_t oW    = 0;
  const size_t oY    = oW  + (size_t)320*1024;        // Wcat
  const size_t oK    = oY  + (size_t)MM*320;          // Y (reused below)
  const size_t oV    = oK  + (size_t)MM*64;
  const size_t oQ    = oV  + (size_t)MM*64;
  const size_t oNU   = oQ  + (size_t)MM*64;
  const size_t oPW   = oNU + (size_t)MM*64;
  const size_t oSCL  = oPW + (size_t)MM*3;
  const size_t oCNS  = oSCL + (size_t)MM*4;
  const size_t oOB   = oCNS + MM;
  // Y region reused after post_kernel:
  const size_t oOBASE = oY;
  const size_t oE     = oY + (size_t)MM*64;

  pack_w<<<1280, 256, 0, stream>>>(Wk, Wv, Wq, ir_w1, pw, ws + oW);
  gemm1<<<dim3(128, 5), 256, 0, stream>>>(x, ws + oW, ws + oY);
  post_kernel<<<1024, 256, 0, stream>>>(ws + oY, nm_w1, nm_b1, nm_w2, nm_b2,
                                        ir_b1, ir_w2, ir_b2, sap,
                                        ws + oK, ws + oV, ws + oQ, ws + oNU,
                                        ws + oPW, ws + oSCL);
  scan_kernel<<<512, 64, 0, stream>>>(ws + oK, ws + oQ, ws + oV, ws + oSCL,
                                      fap, sap, ws + oOBASE, ws + oE);
  err_kernel<<<4096, 256, 0, stream>>>(ws + oE, ws + oCNS);
  nsout_kernel<<<8, 64, 0, stream>>>(ws + oCNS, ws + oNU, ws + oOBASE,
                                     ws + oPW, ws + oOB);
  out_gemm<<<dim3(8, 256), 256, 0, stream>>>(ws + oOB, Wo, normw, out);
}

// Round 3
// 753.846 us; speedup vs baseline: 1.8582x; 1.6954x over previous
//
#include <hip/hip_runtime.h>
#include <hip/hip_bf16.h>
#include <math.h>

// Problem constants (match reference)
#define BB 8
#define SS 2048
#define DD 1024
#define DS 64
#define MM (BB*SS)   // 16384

// ---------------- helpers ----------------

__device__ __forceinline__ float4 ld4(const float* p) { return *(const float4*)p; }

template<int CTRL>
__device__ __forceinline__ float dppadd(float x) {
  int v = __builtin_amdgcn_update_dpp(0, __float_as_int(x), CTRL, 0xf, 0xf, true);
  return x + __int_as_float(v);
}

// xor-16 / xor-32 butterfly-add stages.
// permlane16_swap(x,x): ret0 = [G1,G1,G3,G3], ret1 = [G0,G0,G2,G2] over 16-lane
// groups -> ret0+ret1 = 32-group-correct partial sums in ALL lanes. Same idea
// for permlane32_swap (halves). Pure VALU, replaces ds_bpermute latency.
__device__ __forceinline__ float xor16add(float x) {
#if defined(__has_builtin) && __has_builtin(__builtin_amdgcn_permlane16_swap)
  auto r = __builtin_amdgcn_permlane16_swap(__float_as_uint(x), __float_as_uint(x), false, false);
  return __uint_as_float(r[0]) + __uint_as_float(r[1]);
#else
  return x + __shfl_xor(x, 16, 64);
#endif
}
__device__ __forceinline__ float xor32add(float x) {
#if defined(__has_builtin) && __has_builtin(__builtin_amdgcn_permlane32_swap)
  auto r = __builtin_amdgcn_permlane32_swap(__float_as_uint(x), __float_as_uint(x), false, false);
  return __uint_as_float(r[0]) + __uint_as_float(r[1]);
#else
  return x + __shfl_xor(x, 32, 64);
#endif
}

// full 64-lane butterfly sum; result valid in all lanes
__device__ __forceinline__ float wsum(float x) {
  x = dppadd<0xB1>(x);   // quad_perm xor1
  x = dppadd<0x4E>(x);   // quad_perm xor2
  x = dppadd<0x141>(x);  // row_half_mirror (completes 8-group)
  x = dppadd<0x140>(x);  // row_mirror      (completes 16-group)
  x = xor16add(x);
  x = xor32add(x);
  return x;
}

__device__ __forceinline__ float gelu_exact(float x) {
  return 0.5f * x * (1.f + erff(x * 0.7071067811865476f));
}

// ---------------- k0: pack weights [Wk;Wv;Wq;ir_w1;pw;0-pad] -> Wcat[320][1024]
__global__ __launch_bounds__(256) void pack_w(
    const float* __restrict__ Wk, const float* __restrict__ Wv,
    const float* __restrict__ Wq, const float* __restrict__ ir_w1,
    const float* __restrict__ pw, float* __restrict__ Wcat) {
  int idx = blockIdx.x * 256 + threadIdx.x;   // 320*1024 total
  int r = idx >> 10, c = idx & 1023;
  float val = 0.f;
  if (r < 64)       val = Wk[r*1024 + c];
  else if (r < 128) val = Wv[(r-64)*1024 + c];
  else if (r < 192) val = Wq[(r-128)*1024 + c];
  else if (r < 256) val = ir_w1[(r-192)*1024 + c];
  else if (r < 259) val = pw[(r-256)*1024 + c];
  Wcat[idx] = val;
}

// ---------------- k1: Y[16384][320] = X[16384][1024] @ Wcat[320][1024]^T
__global__ __launch_bounds__(256) void gemm1(
    const float* __restrict__ X, const float* __restrict__ Wcat,
    float* __restrict__ Y) {
  __shared__ float As[32*128];   // [k][m]
  __shared__ float Bs[32*64];    // [k][n]
  const int t  = threadIdx.x;
  const int m0 = blockIdx.x * 128;
  const int n0 = blockIdx.y * 64;
  const int mi = t >> 4, ni = t & 15;
  const int rA = t >> 1, hA = t & 1;
  const int rB = t >> 2, qB = t & 3;
  float acc[8][4];
  #pragma unroll
  for (int i = 0; i < 8; ++i)
    #pragma unroll
    for (int j = 0; j < 4; ++j) acc[i][j] = 0.f;

  for (int k0 = 0; k0 < 1024; k0 += 32) {
    __syncthreads();
    {
      const float* src = X + (size_t)(m0 + rA)*1024 + k0 + hA*16;
      #pragma unroll
      for (int jj = 0; jj < 4; ++jj) {
        float4 xv = ld4(src + jj*4);
        int kk = hA*16 + jj*4;
        As[(kk+0)*128 + rA] = xv.x; As[(kk+1)*128 + rA] = xv.y;
        As[(kk+2)*128 + rA] = xv.z; As[(kk+3)*128 + rA] = xv.w;
      }
      const float* srcB = Wcat + (size_t)(n0 + rB)*1024 + k0 + qB*8;
      #pragma unroll
      for (int jj = 0; jj < 2; ++jj) {
        float4 bv = ld4(srcB + jj*4);
        int kb = qB*8 + jj*4;
        Bs[(kb+0)*64 + rB] = bv.x; Bs[(kb+1)*64 + rB] = bv.y;
        Bs[(kb+2)*64 + rB] = bv.z; Bs[(kb+3)*64 + rB] = bv.w;
      }
    }
    __syncthreads();
    #pragma unroll
    for (int kk = 0; kk < 32; ++kk) {
      float a[8], bv[4];
      float4 a0 = *(const float4*)&As[kk*128 + mi*8];
      float4 a1 = *(const float4*)&As[kk*128 + mi*8 + 4];
      float4 b0 = *(const float4*)&Bs[kk*64 + ni*4];
      a[0]=a0.x; a[1]=a0.y; a[2]=a0.z; a[3]=a0.w;
      a[4]=a1.x; a[5]=a1.y; a[6]=a1.z; a[7]=a1.w;
      bv[0]=b0.x; bv[1]=b0.y; bv[2]=b0.z; bv[3]=b0.w;
      #pragma unroll
      for (int im = 0; im < 8; ++im)
        #pragma unroll
        for (int in = 0; in < 4; ++in)
          acc[im][in] = fmaf(a[im], bv[in], acc[im][in]);
    }
  }
  #pragma unroll
  for (int im = 0; im < 8; ++im) {
    float4 o; o.x = acc[im][0]; o.y = acc[im][1]; o.z = acc[im][2]; o.w = acc[im][3];
    *(float4*)&Y[(size_t)(m0 + mi*8 + im)*320 + n0 + ni*4] = o;
  }
}

// ---------------- k2: per-token postprocess
__global__ __launch_bounds__(256) void post_kernel(
    const float* __restrict__ Y,
    const float* __restrict__ nm_w1, const float* __restrict__ nm_b1,
    const float* __restrict__ nm_w2, const float* __restrict__ nm_b2,
    const float* __restrict__ ir_b1, const float* __restrict__ ir_w2,
    const float* __restrict__ ir_b2, const float* __restrict__ sap,
    float* __restrict__ K, float* __restrict__ V, float* __restrict__ Q,
    float* __restrict__ NU, float* __restrict__ PW,
    float* __restrict__ SCL) {
  __shared__ float w1s[128*65];
  __shared__ float w2s[64*129];
  __shared__ float vbuf[4][64];
  __shared__ float h1buf[4][128];
  const int tid = threadIdx.x, wid = tid >> 6, l = tid & 63;
  for (int i = tid; i < 128*64; i += 256) w1s[(i>>6)*65 + (i&63)]  = nm_w1[i];
  for (int i = tid; i < 64*128; i += 256) w2s[(i>>7)*129 + (i&127)] = nm_w2[i];
  __syncthreads();
  const float sa   = *sap;
  const float b1a  = nm_b1[l], b1b = nm_b1[64+l], b2l = nm_b2[l];
  const float irb1 = ir_b1[l], irw2 = ir_w2[l],  irb2 = ir_b2[0];
  for (int r = 0; r < 4; ++r) {
    const int tok = blockIdx.x*16 + r*4 + wid;
    const float* yr = Y + (size_t)tok*320;
    float kr = yr[l], vr = yr[64+l], qr = yr[128+l], hr = yr[192+l];
    float rk = 1.f / fmaxf(sqrtf(wsum(kr*kr)), 1e-12f);
    float rq = 1.f / fmaxf(sqrtf(wsum(qr*qr)), 1e-12f);
    float kn = kr*rk, qn = qr*rq;
    float qk = wsum(kn*qn);
    float g  = gelu_exact(hr + irb1);
    float logit = wsum(g*irw2) + irb2;
    float imp = 1.f/(1.f+expf(-logit));
    float bs  = (imp > 0.5f) ? (1.f - sa) : 0.f;   // (1-slow_alpha)*u_slow
    K[(size_t)tok*64+l] = kn; V[(size_t)tok*64+l] = vr; Q[(size_t)tok*64+l] = qn;
    vbuf[wid][l] = vr;
    __syncthreads();
    float h1a = b1a, h1b = b1b;
    #pragma unroll 8
    for (int c = 0; c < 64; ++c) {
      float vv = vbuf[wid][c];
      h1a = fmaf(w1s[l*65 + c], vv, h1a);
      h1b = fmaf(w1s[(64+l)*65 + c], vv, h1b);
    }
    h1buf[wid][l]    = gelu_exact(h1a);
    h1buf[wid][64+l] = gelu_exact(h1b);
    __syncthreads();
    float nu = b2l;
    #pragma unroll 8
    for (int j = 0; j < 128; ++j) nu = fmaf(w2s[l*129 + j], h1buf[wid][j], nu);
    NU[(size_t)tok*64+l] = nu;
    float p0 = yr[256], p1 = yr[257], p2 = yr[258];
    float mx = fmaxf(p0, fmaxf(p1, p2));
    float e0 = expf(p0-mx), e1 = expf(p1-mx), e2 = expf(p2-mx);
    float inv = 1.f/(e0+e1+e2);
    if (l == 0) {
      PW[(size_t)tok*3]   = e0*inv;
      float4 s; s.x = qk; s.y = bs; s.z = e0*inv; s.w = e1*inv;
      *(float4*)&SCL[(size_t)tok*4] = s;
    }
    else if (l == 1)   PW[(size_t)tok*3+1] = e1*inv;
    else if (l == 2)   PW[(size_t)tok*3+2] = e2*inv;
    __syncthreads();
  }
}

// ---------------- k3: sequential scan, column-parallel, explicit ping-pong
// pipeline. One wave per (b, v). Lane l holds fH[l][v], sH[l][v].
// ISSUE loads 8 tokens into one register set with immediate offsets off
// running pointers, then sched_barrier(0) pins the issue point so the
// compiler cannot sink the loads into the dependent compute body.
__global__ __launch_bounds__(64) void scan_kernel(
    const float* __restrict__ K, const float* __restrict__ Q,
    const float* __restrict__ V, const float* __restrict__ SCL,
    const float* __restrict__ fap, const float* __restrict__ sap,
    float* __restrict__ OBASE, float* __restrict__ E) {
  const int b = blockIdx.x >> 6;
  const int v = blockIdx.x & 63;
  const int l = threadIdx.x;
  const float fa = *fap, sa = *sap;
  const float omfa = 1.f - fa;
  const size_t base = (size_t)b * SS * 64;
  const float* kp = K + base + l;
  const float* qp = Q + base + l;
  const float* vp = V + base + v;
  const float* sp = SCL + (size_t)b * SS * 4;
  // combined store base: lane 0 -> OBASE, lane 32 -> E (others exec-masked off)
  float* stp = ((l == 32) ? E : OBASE) + base + v;

  float fH = 0.f, sH = 0.f;
  float kA[8], qA[8], vA[8], kB[8], qB[8], vB[8];
  float4 sA[8], sB[8];

#define ISSUE(KX,QX,VX,SX)                              \
  { _Pragma("unroll")                                    \
    for (int i = 0; i < 8; ++i) {                        \
      KX[i] = kp[i*64]; QX[i] = qp[i*64];                \
      VX[i] = vp[i*64];                                  \
      SX[i] = *(const float4*)(sp + i*4);                \
    }                                                    \
    kp += 512; qp += 512; vp += 512; sp += 32;           \
    __builtin_amdgcn_sched_barrier(0); }

#define STEP(KX,QX,VX,SX,i)                              \
  { const float kc = KX[i], qc = QX[i], vc = VX[i];      \
    const float qkc = SX[i].x, bsc = SX[i].y;            \
    const float p0c = SX[i].z, p1c = SX[i].w;            \
    float pf  = wsum(kc*fH);                             \
    float pq  = wsum(qc*fH);                             \
    float ps  = wsum(kc*sH);                             \
    float pqs = wsum(qc*sH);                             \
    float ef = vc - pf, es = vc - ps;                    \
    float pd = vc - 0.5f*(pq + pqs);                     \
    fH = fmaf(omfa*kc, ef, fa*fH);                       \
    sH = fmaf(bsc*kc, es, sa*sH);                        \
    float qfn = fmaf(omfa*qkc, ef, fa*pq);               \
    float qsn = fmaf(bsc*qkc,  es, sa*pqs);              \
    val[i] = (l == 32) ? pd*pd : p0c*qfn + p1c*qsn; }

#define BODY(KX,QX,VX,SX)                                \
  { float val[8];                                        \
    STEP(KX,QX,VX,SX,0) STEP(KX,QX,VX,SX,1)              \
    STEP(KX,QX,VX,SX,2) STEP(KX,QX,VX,SX,3)              \
    STEP(KX,QX,VX,SX,4) STEP(KX,QX,VX,SX,5)              \
    STEP(KX,QX,VX,SX,6) STEP(KX,QX,VX,SX,7)              \
    if (l == 0 || l == 32) {                             \
      _Pragma("unroll")                                  \
      for (int i = 0; i < 8; ++i) stp[i*64] = val[i];    \
    }                                                    \
    stp += 512; }

  ISSUE(kA,qA,vA,sA)
  for (int T = 0; T < SS; T += 16) {
    ISSUE(kB,qB,vB,sB)   // tokens [T+8,  T+16)
    BODY (kA,qA,vA,sA)   // tokens [T,    T+8)
    ISSUE(kA,qA,vA,sA)   // tokens [T+16, T+24) (tail reads run past region: harmless, unused)
    BODY (kB,qB,vB,sB)   // tokens [T+8,  T+16)
  }
#undef ISSUE
#undef STEP
#undef BODY
}

// ---------------- k4: err reduce -> ns-gate coefficient c = 0.1*u_neu
__global__ __launch_bounds__(256) void err_kernel(
    const float* __restrict__ E, float* __restrict__ CNS) {
  int row = blockIdx.x*4 + (threadIdx.x >> 6);
  int l = threadIdx.x & 63;
  float s = wsum(E[(size_t)row*64 + l]);
  if (l == 0) {
    float z = s / (1.0f + 1e-6f);          // TEMP + 1e-6
    float sg = 1.f/(1.f+expf(-z));
    CNS[row] = (sg > 0.7f) ? 0.1f : 0.f;
  }
}

// ---------------- k5: ns scan + o assembly, software-pipelined
#define BW 16
__device__ __forceinline__ void loadw(int b, int t0, int v,
    const float* __restrict__ CNS, const float* __restrict__ NU,
    const float* __restrict__ OBASE, const float* __restrict__ PW,
    float* c, float* nu, float* ob, float* p2) {
  #pragma unroll
  for (int i = 0; i < BW; ++i) {
    size_t bt = (size_t)b*SS + (t0 + i);
    c[i]  = CNS[bt];
    nu[i] = NU[bt*64 + v];
    ob[i] = OBASE[bt*64 + v];
    p2[i] = PW[bt*3 + 2];
  }
}
__device__ __forceinline__ float procw(int b, int t0, int v, float ns,
    const float* c, const float* nu, const float* ob, const float* p2,
    float* __restrict__ OB) {
  #pragma unroll
  for (int i = 0; i < BW; ++i) {
    float cn = c[i]*nu[i];
    float a  = 1.f - c[i];
    ns = fmaf(a, ns, cn);                 // ns = (1-c)*ns + c*nu
    float o = fmaf(p2[i], ns, ob[i]);
    OB[((size_t)b*SS + (t0+i))*64 + v] = o;
  }
  return ns;
}
__global__ __launch_bounds__(64) void nsout_kernel(
    const float* __restrict__ CNS, const float* __restrict__ NU,
    const float* __restrict__ OBASE, const float* __restrict__ PW,
    float* __restrict__ OB) {
  const int b = blockIdx.x, v = threadIdx.x;
  float cA[BW],nA[BW],oA[BW],pA[BW], cB[BW],nB[BW],oB[BW],pB[BW];
  loadw(b, 0, v, CNS, NU, OBASE, PW, cA, nA, oA, pA);
  float ns = 0.f;
  for (int t0 = 0; t0 < SS; t0 += 2*BW) {
    int tB = t0 + BW;
    loadw(b, tB, v, CNS, NU, OBASE, PW, cB, nB, oB, pB);
    ns = procw(b, t0, v, ns, cA, nA, oA, pA, OB);
    int tA2 = t0 + 2*BW; if (tA2 > SS - BW) tA2 = SS - BW;
    loadw(b, tA2, v, CNS, NU, OBASE, PW, cA, nA, oA, pA);
    ns = procw(b, tB, v, ns, cB, nB, oB, pB, OB);
  }
}

// ---------------- k6: fused RMSNorm + out = normed @ Wo^T
__global__ __launch_bounds__(256) void out_gemm(
    const float* __restrict__ OB, const float* __restrict__ Wo,
    const float* __restrict__ normw, float* __restrict__ out) {
  __shared__ float As[64*64];    // [k][m]
  __shared__ float Bs[64*128];   // [k][n]
  const int t  = threadIdx.x;
  const int m0 = blockIdx.y * 64;
  const int n0 = blockIdx.x * 128;
  {
    int r = t >> 2, q4 = t & 3;
    const float* src = OB + (size_t)(m0 + r)*64 + q4*16;
    float4 x0 = ld4(src), x1 = ld4(src+4), x2 = ld4(src+8), x3 = ld4(src+12);
    float ss = x0.x*x0.x+x0.y*x0.y+x0.z*x0.z+x0.w*x0.w
             + x1.x*x1.x+x1.y*x1.y+x1.z*x1.z+x1.w*x1.w
             + x2.x*x2.x+x2.y*x2.y+x2.z*x2.z+x2.w*x2.w
             + x3.x*x3.x+x3.y*x3.y+x3.z*x3.z+x3.w*x3.w;
    ss += __shfl_xor(ss, 1, 64);
    ss += __shfl_xor(ss, 2, 64);
    float rms = rsqrtf(ss * (1.f/64.f) + 1e-6f);
    const float* nw = normw + q4*16;
    float4 w0 = ld4(nw), w1 = ld4(nw+4), w2 = ld4(nw+8), w3 = ld4(nw+12);
    int kbase = q4*16;
    As[(kbase+ 0)*64+r]=x0.x*rms*w0.x; As[(kbase+ 1)*64+r]=x0.y*rms*w0.y;
    As[(kbase+ 2)*64+r]=x0.z*rms*w0.z; As[(kbase+ 3)*64+r]=x0.w*rms*w0.w;
    As[(kbase+ 4)*64+r]=x1.x*rms*w1.x; As[(kbase+ 5)*64+r]=x1.y*rms*w1.y;
    As[(kbase+ 6)*64+r]=x1.z*rms*w1.z; As[(kbase+ 7)*64+r]=x1.w*rms*w1.w;
    As[(kbase+ 8)*64+r]=x2.x*rms*w2.x; As[(kbase+ 9)*64+r]=x2.y*rms*w2.y;
    As[(kbase+10)*64+r]=x2.z*rms*w2.z; As[(kbase+11)*64+r]=x2.w*rms*w2.w;
    As[(kbase+12)*64+r]=x3.x*rms*w3.x; As[(kbase+13)*64+r]=x3.y*rms*w3.y;
    As[(kbase+14)*64+r]=x3.z*rms*w3.z; As[(kbase+15)*64+r]=x3.w*rms*w3.w;
  }
  {
    int rw = t >> 1, half = t & 1;
    const float* src = Wo + (size_t)(n0 + rw)*64 + half*32;
    #pragma unroll
    for (int j = 0; j < 8; ++j) {
      float4 w = ld4(src + j*4);
      int k = half*32 + j*4;
      Bs[(k+0)*128+rw] = w.x; Bs[(k+1)*128+rw] = w.y;
      Bs[(k+2)*128+rw] = w.z; Bs[(k+3)*128+rw] = w.w;
    }
  }
  __syncthreads();
  const int mi = t >> 5, ni = t & 31;
  float acc[8][4];
  #pragma unroll
  for (int i = 0; i < 8; ++i)
    #pragma unroll
    for (int j = 0; j < 4; ++j) acc[i][j] = 0.f;
  #pragma unroll 8
  for (int k = 0; k < 64; ++k) {
    float a[8], bv[4];
    float4 a0 = *(const float4*)&As[k*64 + mi*8];
    float4 a1 = *(const float4*)&As[k*64 + mi*8 + 4];
    float4 b0 = *(const float4*)&Bs[k*128 + ni*4];
    a[0]=a0.x; a[1]=a0.y; a[2]=a0.z; a[3]=a0.w;
    a[4]=a1.x; a[5]=a1.y; a[6]=a1.z; a[7]=a1.w;
    bv[0]=b0.x; bv[1]=b0.y; bv[2]=b0.z; bv[3]=b0.w;
    #pragma unroll
    for (int im = 0; im < 8; ++im)
      #pragma unroll
      for (int in = 0; in < 4; ++in)
        acc[im][in] = fmaf(a[im], bv[in], acc[im][in]);
  }
  #pragma unroll
  for (int im = 0; im < 8; ++im) {
    float4 o; o.x=acc[im][0]; o.y=acc[im][1]; o.z=acc[im][2]; o.w=acc[im][3];
    *(float4*)&out[(size_t)(m0 + mi*8 + im)*1024 + n0 + ni*4] = o;
  }
}

// ---------------- launcher ----------------
extern "C" void kernel_launch(void* const* d_in, const int* in_sizes, int n_in,
                              void* d_out, int out_size, void* d_ws, size_t ws_size,
                              hipStream_t stream) {
  const float* x     = (const float*)d_in[0];
  const float* Wk    = (const float*)d_in[1];
  const float* Wv    = (const float*)d_in[2];
  const float* Wq    = (const float*)d_in[3];
  const float* fap   = (const float*)d_in[4];
  const float* sap   = (const float*)d_in[5];
  const float* nm_w1 = (const float*)d_in[6];
  const float* nm_b1 = (const float*)d_in[7];
  const float* nm_w2 = (const float*)d_in[8];
  const float* nm_b2 = (const float*)d_in[9];
  const float* ir_w1 = (const float*)d_in[10];
  const float* ir_b1 = (const float*)d_in[11];
  const float* ir_w2 = (const float*)d_in[12];
  const float* ir_b2 = (const float*)d_in[13];
  const float* pw    = (const float*)d_in[14];
  const float* Wo    = (const float*)d_in[15];
  const float* normw = (const float*)d_in[16];
  float* out = (float*)d_out;
  float* ws  = (float*)d_ws;

  // workspace layout (floats)
  const size_t oW    = 0;
  const size_t oY    = oW  + (size_t)320*1024;        // Wcat
  const size_t oK    = oY  + (size_t)MM*320;          // Y (reused below)
  const size_t oV    = oK  + (size_t)MM*64;
  const size_t oQ    = oV  + (size_t)MM*64;
  const size_t oNU   = oQ  + (size_t)MM*64;
  const size_t oPW   = oNU + (size_t)MM*64;
  const size_t oSCL  = oPW + (size_t)MM*3;
  const size_t oCNS  = oSCL + (size_t)MM*4;
  const size_t oOB   = oCNS + MM;
  // Y region reused after post_kernel:
  const size_t oOBASE = oY;
  const size_t oE     = oY + (size_t)MM*64;

  pack_w<<<1280, 256, 0, stream>>>(Wk, Wv, Wq, ir_w1, pw, ws + oW);
  gemm1<<<dim3(128, 5), 256, 0, stream>>>(x, ws + oW, ws + oY);
  post_kernel<<<1024, 256, 0, stream>>>(ws + oY, nm_w1, nm_b1, nm_w2, nm_b2,
                                        ir_b1, ir_w2, ir_b2, sap,
                                        ws + oK, ws + oV, ws + oQ, ws + oNU,
                                        ws + oPW, ws + oSCL);
  scan_kernel<<<512, 64, 0, stream>>>(ws + oK, ws + oQ, ws + oV, ws + oSCL,
                                      fap, sap, ws + oOBASE, ws + oE);
  err_kernel<<<4096, 256, 0, stream>>>(ws + oE, ws + oCNS);
  nsout_kernel<<<8, 64, 0, stream>>>(ws + oCNS, ws + oNU, ws + oOBASE,
                                     ws + oPW, ws + oOB);
  out_gemm<<<dim3(8, 256), 256, 0, stream>>>(ws + oOB, Wo, normw, out);
}

// Round 6
// 738.457 us; speedup vs baseline: 1.8969x; 1.0208x over previous
//
#include <hip/hip_runtime.h>
#include <hip/hip_bf16.h>
#include <math.h>

// Problem constants (match reference)
#define BB 8
#define SS 2048
#define DD 1024
#define DS 64
#define MM (BB*SS)   // 16384

// ---------------- helpers ----------------

__device__ __forceinline__ float4 ld4(const float* p) { return *(const float4*)p; }

template<int CTRL>
__device__ __forceinline__ float dppadd(float x) {
  int v = __builtin_amdgcn_update_dpp(0, __float_as_int(x), CTRL, 0xf, 0xf, true);
  return x + __int_as_float(v);
}

// xor-16 / xor-32 butterfly-add stages via gfx950 permlane swaps (pure VALU).
__device__ __forceinline__ float xor16add(float x) {
#if defined(__has_builtin) && __has_builtin(__builtin_amdgcn_permlane16_swap)
  auto r = __builtin_amdgcn_permlane16_swap(__float_as_uint(x), __float_as_uint(x), false, false);
  return __uint_as_float(r[0]) + __uint_as_float(r[1]);
#else
  return x + __shfl_xor(x, 16, 64);
#endif
}
__device__ __forceinline__ float xor32add(float x) {
#if defined(__has_builtin) && __has_builtin(__builtin_amdgcn_permlane32_swap)
  auto r = __builtin_amdgcn_permlane32_swap(__float_as_uint(x), __float_as_uint(x), false, false);
  return __uint_as_float(r[0]) + __uint_as_float(r[1]);
#else
  return x + __shfl_xor(x, 32, 64);
#endif
}

// full 64-lane butterfly sum; result valid in all lanes
__device__ __forceinline__ float wsum(float x) {
  x = dppadd<0xB1>(x);   // quad_perm xor1
  x = dppadd<0x4E>(x);   // quad_perm xor2
  x = dppadd<0x141>(x);  // row_half_mirror (completes 8-group)
  x = dppadd<0x140>(x);  // row_mirror      (completes 16-group)
  x = xor16add(x);
  x = xor32add(x);
  return x;
}

__device__ __forceinline__ float gelu_exact(float x) {
  return 0.5f * x * (1.f + erff(x * 0.7071067811865476f));
}

// global -> LDS async staging (data lands at LDS base + lane*size)
__device__ __forceinline__ void gll16(const float* g, float* l) {
  __builtin_amdgcn_global_load_lds(
      (const __attribute__((address_space(1))) void*)g,
      (__attribute__((address_space(3))) void*)l, 16, 0, 0);
}
__device__ __forceinline__ void gll4(const float* g, float* l) {
  __builtin_amdgcn_global_load_lds(
      (const __attribute__((address_space(1))) void*)g,
      (__attribute__((address_space(3))) void*)l, 4, 0, 0);
}

// ---------------- k0: pack weights [Wk;Wv;Wq;ir_w1;pw;0-pad] -> Wcat[320][1024]
__global__ __launch_bounds__(256) void pack_w(
    const float* __restrict__ Wk, const float* __restrict__ Wv,
    const float* __restrict__ Wq, const float* __restrict__ ir_w1,
    const float* __restrict__ pw, float* __restrict__ Wcat) {
  int idx = blockIdx.x * 256 + threadIdx.x;   // 320*1024 total
  int r = idx >> 10, c = idx & 1023;
  float val = 0.f;
  if (r < 64)       val = Wk[r*1024 + c];
  else if (r < 128) val = Wv[(r-64)*1024 + c];
  else if (r < 192) val = Wq[(r-128)*1024 + c];
  else if (r < 256) val = ir_w1[(r-192)*1024 + c];
  else if (r < 259) val = pw[(r-256)*1024 + c];
  Wcat[idx] = val;
}

// ---------------- k1: Y[16384][320] = X[16384][1024] @ Wcat[320][1024]^T
__global__ __launch_bounds__(256) void gemm1(
    const float* __restrict__ X, const float* __restrict__ Wcat,
    float* __restrict__ Y) {
  __shared__ float As[32*128];   // [k][m]
  __shared__ float Bs[32*64];    // [k][n]
  const int t  = threadIdx.x;
  const int m0 = blockIdx.x * 128;
  const int n0 = blockIdx.y * 64;
  const int mi = t >> 4, ni = t & 15;
  const int rA = t >> 1, hA = t & 1;
  const int rB = t >> 2, qB = t & 3;
  float acc[8][4];
  #pragma unroll
  for (int i = 0; i < 8; ++i)
    #pragma unroll
    for (int j = 0; j < 4; ++j) acc[i][j] = 0.f;

  for (int k0 = 0; k0 < 1024; k0 += 32) {
    __syncthreads();
    {
      const float* src = X + (size_t)(m0 + rA)*1024 + k0 + hA*16;
      #pragma unroll
      for (int jj = 0; jj < 4; ++jj) {
        float4 xv = ld4(src + jj*4);
        int kk = hA*16 + jj*4;
        As[(kk+0)*128 + rA] = xv.x; As[(kk+1)*128 + rA] = xv.y;
        As[(kk+2)*128 + rA] = xv.z; As[(kk+3)*128 + rA] = xv.w;
      }
      const float* srcB = Wcat + (size_t)(n0 + rB)*1024 + k0 + qB*8;
      #pragma unroll
      for (int jj = 0; jj < 2; ++jj) {
        float4 bv = ld4(srcB + jj*4);
        int kb = qB*8 + jj*4;
        Bs[(kb+0)*64 + rB] = bv.x; Bs[(kb+1)*64 + rB] = bv.y;
        Bs[(kb+2)*64 + rB] = bv.z; Bs[(kb+3)*64 + rB] = bv.w;
      }
    }
    __syncthreads();
    #pragma unroll
    for (int kk = 0; kk < 32; ++kk) {
      float a[8], bv[4];
      float4 a0 = *(const float4*)&As[kk*128 + mi*8];
      float4 a1 = *(const float4*)&As[kk*128 + mi*8 + 4];
      float4 b0 = *(const float4*)&Bs[kk*64 + ni*4];
      a[0]=a0.x; a[1]=a0.y; a[2]=a0.z; a[3]=a0.w;
      a[4]=a1.x; a[5]=a1.y; a[6]=a1.z; a[7]=a1.w;
      bv[0]=b0.x; bv[1]=b0.y; bv[2]=b0.z; bv[3]=b0.w;
      #pragma unroll
      for (int im = 0; im < 8; ++im)
        #pragma unroll
        for (int in = 0; in < 4; ++in)
          acc[im][in] = fmaf(a[im], bv[in], acc[im][in]);
    }
  }
  #pragma unroll
  for (int im = 0; im < 8; ++im) {
    float4 o; o.x = acc[im][0]; o.y = acc[im][1]; o.z = acc[im][2]; o.w = acc[im][3];
    *(float4*)&Y[(size_t)(m0 + mi*8 + im)*320 + n0 + ni*4] = o;
  }
}

// ---------------- k2: per-token postprocess
__global__ __launch_bounds__(256) void post_kernel(
    const float* __restrict__ Y,
    const float* __restrict__ nm_w1, const float* __restrict__ nm_b1,
    const float* __restrict__ nm_w2, const float* __restrict__ nm_b2,
    const float* __restrict__ ir_b1, const float* __restrict__ ir_w2,
    const float* __restrict__ ir_b2, const float* __restrict__ sap,
    float* __restrict__ K, float* __restrict__ V, float* __restrict__ Q,
    float* __restrict__ NU, float* __restrict__ PW,
    float* __restrict__ SCL) {
  __shared__ float w1s[128*65];
  __shared__ float w2s[64*129];
  __shared__ float vbuf[4][64];
  __shared__ float h1buf[4][128];
  const int tid = threadIdx.x, wid = tid >> 6, l = tid & 63;
  for (int i = tid; i < 128*64; i += 256) w1s[(i>>6)*65 + (i&63)]  = nm_w1[i];
  for (int i = tid; i < 64*128; i += 256) w2s[(i>>7)*129 + (i&127)] = nm_w2[i];
  __syncthreads();
  const float sa   = *sap;
  const float b1a  = nm_b1[l], b1b = nm_b1[64+l], b2l = nm_b2[l];
  const float irb1 = ir_b1[l], irw2 = ir_w2[l],  irb2 = ir_b2[0];
  for (int r = 0; r < 4; ++r) {
    const int tok = blockIdx.x*16 + r*4 + wid;
    const float* yr = Y + (size_t)tok*320;
    float kr = yr[l], vr = yr[64+l], qr = yr[128+l], hr = yr[192+l];
    float rk = 1.f / fmaxf(sqrtf(wsum(kr*kr)), 1e-12f);
    float rq = 1.f / fmaxf(sqrtf(wsum(qr*qr)), 1e-12f);
    float kn = kr*rk, qn = qr*rq;
    float qk = wsum(kn*qn);
    float g  = gelu_exact(hr + irb1);
    float logit = wsum(g*irw2) + irb2;
    float imp = 1.f/(1.f+expf(-logit));
    float bs  = (imp > 0.5f) ? (1.f - sa) : 0.f;   // (1-slow_alpha)*u_slow
    K[(size_t)tok*64+l] = kn; V[(size_t)tok*64+l] = vr; Q[(size_t)tok*64+l] = qn;
    vbuf[wid][l] = vr;
    __syncthreads();
    float h1a = b1a, h1b = b1b;
    #pragma unroll 8
    for (int c = 0; c < 64; ++c) {
      float vv = vbuf[wid][c];
      h1a = fmaf(w1s[l*65 + c], vv, h1a);
      h1b = fmaf(w1s[(64+l)*65 + c], vv, h1b);
    }
    h1buf[wid][l]    = gelu_exact(h1a);
    h1buf[wid][64+l] = gelu_exact(h1b);
    __syncthreads();
    float nu = b2l;
    #pragma unroll 8
    for (int j = 0; j < 128; ++j) nu = fmaf(w2s[l*129 + j], h1buf[wid][j], nu);
    NU[(size_t)tok*64+l] = nu;
    float p0 = yr[256], p1 = yr[257], p2 = yr[258];
    float mx = fmaxf(p0, fmaxf(p1, p2));
    float e0 = expf(p0-mx), e1 = expf(p1-mx), e2 = expf(p2-mx);
    float inv = 1.f/(e0+e1+e2);
    if (l == 0) {
      PW[(size_t)tok*3]   = e0*inv;
      float4 s; s.x = qk; s.y = bs; s.z = e0*inv; s.w = e1*inv;
      *(float4*)&SCL[(size_t)tok*4] = s;
    }
    else if (l == 1)   PW[(size_t)tok*3+1] = e1*inv;
    else if (l == 2)   PW[(size_t)tok*3+2] = e2*inv;
    __syncthreads();
  }
}

// ---------------- k2b: V[b][t][v] -> VT[b][v][t] (64x64 LDS tiles)
__global__ __launch_bounds__(256) void transpose_v(
    const float* __restrict__ V, float* __restrict__ VT) {
  __shared__ float tile[64][65];
  const int b  = blockIdx.x >> 5;       // 8 batches
  const int t0 = (blockIdx.x & 31) * 64; // 32 t-tiles
  const int tid = threadIdx.x;
  const int rr = tid >> 6, cc = tid & 63;
  #pragma unroll
  for (int r4 = 0; r4 < 64; r4 += 4) {
    int t = t0 + r4 + rr;
    tile[r4 + rr][cc] = V[((size_t)b*SS + t)*64 + cc];
  }
  __syncthreads();
  #pragma unroll
  for (int r4 = 0; r4 < 64; r4 += 4) {
    int vv = r4 + rr;
    VT[((size_t)b*64 + vv)*SS + t0 + cc] = tile[cc][vv];
  }
}

// ---------------- k3: sequential scan, column-parallel, LDS double-buffer.
// One wave per (b, v). Lane l holds fH[l][v], sH[l][v].
// Staging lands in LDS via global_load_lds (no SSA registers for regalloc to
// move -> immune to the R4/R5 async-register hazard). Depth-1 pipeline at
// 64-token chunk granularity: stage chunk c+1 into buf^1, compute chunk c
// from buf (~9600 cy >> DMA latency), then one vmcnt(0) drain per chunk.
#define CH 64
__global__ __launch_bounds__(64) void scan_kernel(
    const float* __restrict__ K, const float* __restrict__ Q,
    const float* __restrict__ VT, const float* __restrict__ SCL,
    const float* __restrict__ fap, const float* __restrict__ sap,
    float* __restrict__ OBASE, float* __restrict__ E) {
  __shared__ float  lK[2][CH*64];   // 32 KB
  __shared__ float  lQ[2][CH*64];   // 32 KB
  __shared__ float  lV[2][CH];      // 512 B
  __shared__ float4 lS[2][CH];      // 2 KB
  const int b = blockIdx.x >> 6;
  const int v = blockIdx.x & 63;
  const int l = threadIdx.x;
  const float fa = *fap, sa = *sap, omfa = 1.f - fa;
  const size_t base = (size_t)b * SS * 64;
  const float* gK = K + base + l*4;                    // lane covers 16B
  const float* gQ = Q + base + l*4;
  const float* gV = VT + ((size_t)b*64 + v)*SS + l;    // lane covers 4B
  const float* gS = SCL + (size_t)b*SS*4 + l*4;        // lane covers 16B
  float* stp = ((l == 32) ? E : OBASE) + base + v;
  float fH = 0.f, sH = 0.f;

#define STAGE(buf, c) {                                              \
    const float* kc_ = gK + (size_t)(c)*CH*64;                       \
    const float* qc_ = gQ + (size_t)(c)*CH*64;                       \
    _Pragma("unroll")                                                \
    for (int j = 0; j < 16; ++j) {                                   \
      gll16(kc_ + j*256, &lK[buf][j*256]);                           \
      gll16(qc_ + j*256, &lQ[buf][j*256]);                           \
    }                                                                \
    gll4 (gV + (size_t)(c)*CH,   &lV[buf][0]);                       \
    gll16(gS + (size_t)(c)*CH*4, (float*)&lS[buf][0]); }

#define VMDRAIN { asm volatile("s_waitcnt vmcnt(0)" ::: "memory");   \
                  __builtin_amdgcn_sched_barrier(0); }

  STAGE(0, 0)
  VMDRAIN
  int cur = 0;
  for (int c = 0; c < 32; ++c) {
    if (c + 1 < 32) STAGE(cur ^ 1, c + 1)
    #pragma unroll
    for (int t8 = 0; t8 < 8; ++t8) {
      float val[8];
      #pragma unroll
      for (int i = 0; i < 8; ++i) {
        const int t = t8*8 + i;
        float kc = lK[cur][t*64 + l];
        float qc = lQ[cur][t*64 + l];
        float vc = lV[cur][t];
        float4 s = lS[cur][t];
        float pf  = wsum(kc*fH);
        float pq  = wsum(qc*fH);
        float ps  = wsum(kc*sH);
        float pqs = wsum(qc*sH);
        float ef = vc - pf, es = vc - ps;
        float pd = vc - 0.5f*(pq + pqs);
        fH = fmaf(omfa*kc, ef, fa*fH);
        sH = fmaf(s.y*kc, es, sa*sH);
        float qfn = fmaf(omfa*s.x, ef, fa*pq);
        float qsn = fmaf(s.y*s.x,  es, sa*pqs);
        val[i] = (l == 32) ? pd*pd : s.z*qfn + s.w*qsn;
      }
      if (l == 0 || l == 32) {
        #pragma unroll
        for (int i = 0; i < 8; ++i)
          stp[(size_t)(c*CH + t8*8 + i)*64] = val[i];
      }
    }
    VMDRAIN              // chunk c+1's DMA complete before next body
    cur ^= 1;
  }
#undef STAGE
#undef VMDRAIN
}

// ---------------- k4: err reduce -> ns-gate coefficient c = 0.1*u_neu
__global__ __launch_bounds__(256) void err_kernel(
    const float* __restrict__ E, float* __restrict__ CNS) {
  int row = blockIdx.x*4 + (threadIdx.x >> 6);
  int l = threadIdx.x & 63;
  float s = wsum(E[(size_t)row*64 + l]);
  if (l == 0) {
    float z = s / (1.0f + 1e-6f);          // TEMP + 1e-6
    float sg = 1.f/(1.f+expf(-z));
    CNS[row] = (sg > 0.7f) ? 0.1f : 0.f;
  }
}

// ---------------- k5: ns scan + o assembly, software-pipelined
#define BW 16
__device__ __forceinline__ void loadw(int b, int t0, int v,
    const float* __restrict__ CNS, const float* __restrict__ NU,
    const float* __restrict__ OBASE, const float* __restrict__ PW,
    float* c, float* nu, float* ob, float* p2) {
  #pragma unroll
  for (int i = 0; i < BW; ++i) {
    size_t bt = (size_t)b*SS + (t0 + i);
    c[i]  = CNS[bt];
    nu[i] = NU[bt*64 + v];
    ob[i] = OBASE[bt*64 + v];
    p2[i] = PW[bt*3 + 2];
  }
}
__device__ __forceinline__ float procw(int b, int t0, int v, float ns,
    const float* c, const float* nu, const float* ob, const float* p2,
    float* __restrict__ OB) {
  #pragma unroll
  for (int i = 0; i < BW; ++i) {
    float cn = c[i]*nu[i];
    float a  = 1.f - c[i];
    ns = fmaf(a, ns, cn);                 // ns = (1-c)*ns + c*nu
    float o = fmaf(p2[i], ns, ob[i]);
    OB[((size_t)b*SS + (t0+i))*64 + v] = o;
  }
  return ns;
}
__global__ __launch_bounds__(64) void nsout_kernel(
    const float* __restrict__ CNS, const float* __restrict__ NU,
    const float* __restrict__ OBASE, const float* __restrict__ PW,
    float* __restrict__ OB) {
  const int b = blockIdx.x, v = threadIdx.x;
  float cA[BW],nA[BW],oA[BW],pA[BW], cB[BW],nB[BW],oB[BW],pB[BW];
  loadw(b, 0, v, CNS, NU, OBASE, PW, cA, nA, oA, pA);
  float ns = 0.f;
  for (int t0 = 0; t0 < SS; t0 += 2*BW) {
    int tB = t0 + BW;
    loadw(b, tB, v, CNS, NU, OBASE, PW, cB, nB, oB, pB);
    ns = procw(b, t0, v, ns, cA, nA, oA, pA, OB);
    int tA2 = t0 + 2*BW; if (tA2 > SS - BW) tA2 = SS - BW;
    loadw(b, tA2, v, CNS, NU, OBASE, PW, cA, nA, oA, pA);
    ns = procw(b, tB, v, ns, cB, nB, oB, pB, OB);
  }
}

// ---------------- k6: fused RMSNorm + out = normed @ Wo^T
__global__ __launch_bounds__(256) void out_gemm(
    const float* __restrict__ OB, const float* __restrict__ Wo,
    const float* __restrict__ normw, float* __restrict__ out) {
  __shared__ float As[64*64];    // [k][m]
  __shared__ float Bs[64*128];   // [k][n]
  const int t  = threadIdx.x;
  const int m0 = blockIdx.y * 64;
  const int n0 = blockIdx.x * 128;
  {
    int r = t >> 2, q4 = t & 3;
    const float* src = OB + (size_t)(m0 + r)*64 + q4*16;
    float4 x0 = ld4(src), x1 = ld4(src+4), x2 = ld4(src+8), x3 = ld4(src+12);
    float ss = x0.x*x0.x+x0.y*x0.y+x0.z*x0.z+x0.w*x0.w
             + x1.x*x1.x+x1.y*x1.y+x1.z*x1.z+x1.w*x1.w
             + x2.x*x2.x+x2.y*x2.y+x2.z*x2.z+x2.w*x2.w
             + x3.x*x3.x+x3.y*x3.y+x3.z*x3.z+x3.w*x3.w;
    ss += __shfl_xor(ss, 1, 64);
    ss += __shfl_xor(ss, 2, 64);
    float rms = rsqrtf(ss * (1.f/64.f) + 1e-6f);
    const float* nw = normw + q4*16;
    float4 w0 = ld4(nw), w1 = ld4(nw+4), w2 = ld4(nw+8), w3 = ld4(nw+12);
    int kbase = q4*16;
    As[(kbase+ 0)*64+r]=x0.x*rms*w0.x; As[(kbase+ 1)*64+r]=x0.y*rms*w0.y;
    As[(kbase+ 2)*64+r]=x0.z*rms*w0.z; As[(kbase+ 3)*64+r]=x0.w*rms*w0.w;
    As[(kbase+ 4)*64+r]=x1.x*rms*w1.x; As[(kbase+ 5)*64+r]=x1.y*rms*w1.y;
    As[(kbase+ 6)*64+r]=x1.z*rms*w1.z; As[(kbase+ 7)*64+r]=x1.w*rms*w1.w;
    As[(kbase+ 8)*64+r]=x2.x*rms*w2.x; As[(kbase+ 9)*64+r]=x2.y*rms*w2.y;
    As[(kbase+10)*64+r]=x2.z*rms*w2.z; As[(kbase+11)*64+r]=x2.w*rms*w2.w;
    As[(kbase+12)*64+r]=x3.x*rms*w3.x; As[(kbase+13)*64+r]=x3.y*rms*w3.y;
    As[(kbase+14)*64+r]=x3.z*rms*w3.z; As[(kbase+15)*64+r]=x3.w*rms*w3.w;
  }
  {
    int rw = t >> 1, half = t & 1;
    const float* src = Wo + (size_t)(n0 + rw)*64 + half*32;
    #pragma unroll
    for (int j = 0; j < 8; ++j) {
      float4 w = ld4(src + j*4);
      int k = half*32 + j*4;
      Bs[(k+0)*128+rw] = w.x; Bs[(k+1)*128+rw] = w.y;
      Bs[(k+2)*128+rw] = w.z; Bs[(k+3)*128+rw] = w.w;
    }
  }
  __syncthreads();
  const int mi = t >> 5, ni = t & 31;
  float acc[8][4];
  #pragma unroll
  for (int i = 0; i < 8; ++i)
    #pragma unroll
    for (int j = 0; j < 4; ++j) acc[i][j] = 0.f;
  #pragma unroll 8
  for (int k = 0; k < 64; ++k) {
    float a[8], bv[4];
    float4 a0 = *(const float4*)&As[k*64 + mi*8];
    float4 a1 = *(const float4*)&As[k*64 + mi*8 + 4];
    float4 b0 = *(const float4*)&Bs[k*128 + ni*4];
    a[0]=a0.x; a[1]=a0.y; a[2]=a0.z; a[3]=a0.w;
    a[4]=a1.x; a[5]=a1.y; a[6]=a1.z; a[7]=a1.w;
    bv[0]=b0.x; bv[1]=b0.y; bv[2]=b0.z; bv[3]=b0.w;
    #pragma unroll
    for (int im = 0; im < 8; ++im)
      #pragma unroll
      for (int in = 0; in < 4; ++in)
        acc[im][in] = fmaf(a[im], bv[in], acc[im][in]);
  }
  #pragma unroll
  for (int im = 0; im < 8; ++im) {
    float4 o; o.x=acc[im][0]; o.y=acc[im][1]; o.z=acc[im][2]; o.w=acc[im][3];
    *(float4*)&out[(size_t)(m0 + mi*8 + im)*1024 + n0 + ni*4] = o;
  }
}

// ---------------- launcher ----------------
extern "C" void kernel_launch(void* const* d_in, const int* in_sizes, int n_in,
                              void* d_out, int out_size, void* d_ws, size_t ws_size,
                              hipStream_t stream) {
  const float* x     = (const float*)d_in[0];
  const float* Wk    = (const float*)d_in[1];
  const float* Wv    = (const float*)d_in[2];
  const float* Wq    = (const float*)d_in[3];
  const float* fap   = (const float*)d_in[4];
  const float* sap   = (const float*)d_in[5];
  const float* nm_w1 = (const float*)d_in[6];
  const float* nm_b1 = (const float*)d_in[7];
  const float* nm_w2 = (const float*)d_in[8];
  const float* nm_b2 = (const float*)d_in[9];
  const float* ir_w1 = (const float*)d_in[10];
  const float* ir_b1 = (const float*)d_in[11];
  const float* ir_w2 = (const float*)d_in[12];
  const float* ir_b2 = (const float*)d_in[13];
  const float* pw    = (const float*)d_in[14];
  const float* Wo    = (const float*)d_in[15];
  const float* normw = (const float*)d_in[16];
  float* out = (float*)d_out;
  float* ws  = (float*)d_ws;

  // workspace layout (floats)
  const size_t oW    = 0;
  const size_t oY    = oW  + (size_t)320*1024;        // Wcat
  const size_t oK    = oY  + (size_t)MM*320;          // Y (reused below)
  const size_t oV    = oK  + (size_t)MM*64;
  const size_t oQ    = oV  + (size_t)MM*64;
  const size_t oNU   = oQ  + (size_t)MM*64;
  const size_t oPW   = oNU + (size_t)MM*64;
  const size_t oSCL  = oPW + (size_t)MM*3;
  const size_t oCNS  = oSCL + (size_t)MM*4;
  const size_t oOB   = oCNS + MM;
  // Y region reused after post_kernel (Y dead by then):
  const size_t oOBASE = oY;                    // MM*64
  const size_t oE     = oY + (size_t)MM*64;    // MM*64
  const size_t oVT    = oY + (size_t)2*MM*64;  // MM*64 (fits: Y region = MM*320)

  pack_w<<<1280, 256, 0, stream>>>(Wk, Wv, Wq, ir_w1, pw, ws + oW);
  gemm1<<<dim3(128, 5), 256, 0, stream>>>(x, ws + oW, ws + oY);
  post_kernel<<<1024, 256, 0, stream>>>(ws + oY, nm_w1, nm_b1, nm_w2, nm_b2,
                                        ir_b1, ir_w2, ir_b2, sap,
                                        ws + oK, ws + oV, ws + oQ, ws + oNU,
                                        ws + oPW, ws + oSCL);
  transpose_v<<<256, 256, 0, stream>>>(ws + oV, ws + oVT);
  scan_kernel<<<512, 64, 0, stream>>>(ws + oK, ws + oQ, ws + oVT, ws + oSCL,
                                      fap, sap, ws + oOBASE, ws + oE);
  err_kernel<<<4096, 256, 0, stream>>>(ws + oE, ws + oCNS);
  nsout_kernel<<<8, 64, 0, stream>>>(ws + oCNS, ws + oNU, ws + oOBASE,
                                     ws + oPW, ws + oOB);
  out_gemm<<<dim3(8, 256), 256, 0, stream>>>(ws + oOB, Wo, normw, out);
}